// Round 10
// baseline (2889.730 us; speedup 1.0000x reference)
//
#include <hip/hip_runtime.h>
#include <hip/hip_bf16.h>
#include <stdint.h>
#include <math.h>

typedef __attribute__((ext_vector_type(4))) float f32x4;
typedef __attribute__((ext_vector_type(8))) __bf16 bf16x8;
typedef __attribute__((ext_vector_type(8))) uint16_t u16x8;
typedef __attribute__((ext_vector_type(4))) uint32_t u32x4;

__device__ __forceinline__ uint16_t f2bf(float f) {
  union { float f; uint32_t u; } v; v.f = f;
  uint32_t r = v.u + 0x7FFFu + ((v.u >> 16) & 1u);
  return (uint16_t)(r >> 16);
}
__device__ __forceinline__ float bf2f(uint16_t b) {
  union { uint32_t u; float f; } v; v.u = ((uint32_t)b) << 16;
  return v.f;
}

// ---------------------------------------------------------------- converts
__global__ __launch_bounds__(256) void k_conv_x(const float* __restrict__ x,
                                                uint16_t* __restrict__ comb) {
  int i = blockIdx.x * 256 + threadIdx.x;
  int base = i * 8;
  int row = base >> 9;
  int col = base & 511;
  const float* src = x + base;
  f32x4 a = *(const f32x4*)src;
  f32x4 b = *(const f32x4*)(src + 4);
  u16x8 o;
  o[0] = f2bf(a[0]); o[1] = f2bf(a[1]); o[2] = f2bf(a[2]); o[3] = f2bf(a[3]);
  o[4] = f2bf(b[0]); o[5] = f2bf(b[1]); o[6] = f2bf(b[2]); o[7] = f2bf(b[3]);
  *(u16x8*)(comb + (size_t)row * 576 + col) = o;
}

__global__ __launch_bounds__(256) void k_convT(const float* __restrict__ W,
                                               uint16_t* __restrict__ WT,
                                               int K, int N) {
  int i = blockIdx.x * 256 + threadIdx.x;
  if (i < K * N) {
    int k = i / N, n = i % N;
    WT[n * K + k] = f2bf(W[i]);
  }
}

__global__ __launch_bounds__(256) void k_conv(const float* __restrict__ W,
                                              uint16_t* __restrict__ O, int n) {
  int i = blockIdx.x * 256 + threadIdx.x;
  if (i < n) O[i] = f2bf(W[i]);
}

// ---------------------------------------------------------------- fp64-accum GEMM
// C[M,N] = op(A[M,K] @ B[K,N] + bias), fp32 data, fp64 accumulation.
// Encoder proven equivalent (R2==R7 bit-identical) to the f32-replica:
// probe bits carry no decisive divergence.
template <int BM, int BN, int BK, int TM, int TN, bool RELU>
__global__ __launch_bounds__((BM / TM) * (BN / TN))
void k_gemm_f64(const float* __restrict__ A, const float* __restrict__ B,
                const float* __restrict__ bias, float* __restrict__ C,
                int M, int N, int K) {
  constexpr int TX = BN / TN;
  constexpr int TY = BM / TM;
  constexpr int NT = TX * TY;
  __shared__ __align__(16) float As[BK][BM];
  __shared__ __align__(16) float Bs[BK][BN];
  const int t = threadIdx.x;
  const int tx = t % TX, ty = t / TX;
  const int bm = blockIdx.y * BM, bn = blockIdx.x * BN;

  double acc[TM][TN] = {};

  constexpr int AROWS = NT / (BK / 4);
  constexpr int APASS = BM / AROWS;
  constexpr int BROWS = NT / (BN / 4);
  constexpr int BPASS = BK / BROWS;
  const int a_r = t / (BK / 4), a_c = (t % (BK / 4)) * 4;
  const int b_r = t / (BN / 4), b_c = (t % (BN / 4)) * 4;

  for (int kt = 0; kt < K / BK; ++kt) {
    const int k0 = kt * BK;
    __syncthreads();
#pragma unroll
    for (int p = 0; p < APASS; ++p) {
      int r = a_r + p * AROWS;
      f32x4 v = *(const f32x4*)(A + (size_t)(bm + r) * K + k0 + a_c);
      As[a_c + 0][r] = v[0]; As[a_c + 1][r] = v[1];
      As[a_c + 2][r] = v[2]; As[a_c + 3][r] = v[3];
    }
#pragma unroll
    for (int p = 0; p < BPASS; ++p) {
      int r = b_r + p * BROWS;
      *(f32x4*)&Bs[r][b_c] = *(const f32x4*)(B + (size_t)(k0 + r) * N + bn + b_c);
    }
    __syncthreads();
#pragma unroll
    for (int k = 0; k < BK; ++k) {
      double av[TM], bv[TN];
#pragma unroll
      for (int i = 0; i < TM; ++i) av[i] = (double)As[k][ty * TM + i];
#pragma unroll
      for (int j = 0; j < TN; ++j) bv[j] = (double)Bs[k][tx * TN + j];
#pragma unroll
      for (int i = 0; i < TM; ++i)
#pragma unroll
        for (int j = 0; j < TN; ++j)
          acc[i][j] = fma(av[i], bv[j], acc[i][j]);
    }
  }
#pragma unroll
  for (int i = 0; i < TM; ++i) {
    int row = bm + ty * TM + i;
#pragma unroll
    for (int j4 = 0; j4 < TN / 4; ++j4) {
      f32x4 o;
#pragma unroll
      for (int e = 0; e < 4; ++e) {
        int j = j4 * 4 + e;
        int col = bn + tx * TN + j;
        double v = acc[i][j] + (double)bias[col];
        if (RELU) v = v > 0.0 ? v : 0.0;
        o[e] = (float)v;
      }
      *(f32x4*)(C + (size_t)row * N + bn + tx * TN + j4 * 4) = o;
    }
  }
}

// ---------------------------------------------------------------- Hopfield
// f32 state (f64 ruled out by R2/R7/R9). R10 ORDER: numpy pairwise_sum for
// n=64 — the translation's act = (state * w_row).sum(axis=1):
//   r_l = sum_{c=0..7} x[8c+l]   (8 scalar partials, ascending c)
//   act = ((r0+r1)+(r2+r3)) + ((r4+r5)+(r6+r7))
// Distinct from all 7 prior schemes (R4 shared the partials but used the
// AVX hadd tree ((p0+p4)+(p1+p5))+((p2+p6)+(p3+p7))). Products s*w are
// exact sign flips, so only this tree's rounding decides ties — exactly
// what differs between the equivalence classes observed so far.
#define KNIFE_TAU 1e-6f

__device__ __forceinline__ uint64_t retrieve_mask_pw(float* s,
                                                     const float (*w)[64]) {
  for (int it = 0; it < 10; ++it) {
    bool changed = false;
#pragma unroll
    for (int i = 0; i < 64; ++i) {
      float r[8];
#pragma unroll
      for (int l = 0; l < 8; ++l) r[l] = 0.f;
#pragma unroll
      for (int c = 0; c < 8; ++c)
#pragma unroll
        for (int l = 0; l < 8; ++l)
          r[l] = fmaf(s[8 * c + l], w[i][8 * c + l], r[l]);
      float act = ((r[0] + r[1]) + (r[2] + r[3])) +
                  ((r[4] + r[5]) + (r[6] + r[7]));
      float ns = act > 0.f ? 1.f : -1.f;  // np: where(act > 0, 1, -1)
      changed |= (ns != s[i]);
      s[i] = ns;
    }
    if (!__any(changed)) break;  // fixed point: further sweeps are identity
  }
  uint64_t m = 0;
#pragma unroll
  for (int i = 0; i < 64; ++i)
    if (s[i] > 0.f) m |= (1ull << i);
  return m;
}

__global__ __launch_bounds__(128) void k_hopfield(const float* __restrict__ enc,
                                                  const float* __restrict__ hw,
                                                  uint16_t* __restrict__ comb) {
  __shared__ __align__(16) float w[64][64];
  const int t = threadIdx.x;
#pragma unroll
  for (int i = 0; i < 8; ++i)
    ((f32x4*)&w[0][0])[t * 8 + i] = ((const f32x4*)hw)[t * 8 + i];
  __syncthreads();

  const int sid = blockIdx.x * 128 + t;
  const f32x4* er = (const f32x4*)(enc + (size_t)sid * 64);

  uint64_t m0 = 0;
  int knife = -1;
  bool knifePos = false;
#pragma unroll
  for (int g = 0; g < 16; ++g) {
    f32x4 v = er[g];
#pragma unroll
    for (int e = 0; e < 4; ++e) {
      float x = v[e];
      int i = g * 4 + e;
      if (x > 0.f) m0 |= (1ull << i);
      if (fabsf(x) < KNIFE_TAU && knife < 0) { knife = i; knifePos = x > 0.f; }
    }
  }

  float sr[64];
#pragma unroll
  for (int i = 0; i < 64; ++i) sr[i] = ((m0 >> i) & 1) ? 1.f : -1.f;
  if (knife >= 0) sr[knife] = 1.f;
  uint64_t mA = retrieve_mask_pw(sr, w);
  uint64_t m = mA;
  if (knife >= 0) {
#pragma unroll
    for (int i = 0; i < 64; ++i) sr[i] = ((m0 >> i) & 1) ? 1.f : -1.f;
    sr[knife] = -1.f;
    uint64_t mB = retrieve_mask_pw(sr, w);
    if (mA != mB) m = knifePos ? mA : mB;  // exact-sign pick (inert per R9)
  }

  uint16_t* cr = comb + (size_t)sid * 576 + 512;
#pragma unroll
  for (int g = 0; g < 8; ++g) {
    u32x4 o;
#pragma unroll
    for (int p = 0; p < 4; ++p) {
      uint32_t lo = ((m >> (g * 8 + p * 2 + 0)) & 1) ? 0x3F80u : 0u;
      uint32_t hi = ((m >> (g * 8 + p * 2 + 1)) & 1) ? 0x3F800000u : 0u;
      o[p] = lo | hi;
    }
    *(u32x4*)(cr + g * 8) = o;
  }
}

// ---------------------------------------------------------------- bf16 MFMA GEMM
__global__ __launch_bounds__(256)
void k_gemm_bf16(const uint16_t* __restrict__ A, const uint16_t* __restrict__ BT,
                 const float* __restrict__ bias, uint16_t* __restrict__ C,
                 int M, int N, int K, int relu) {
  constexpr int BM = 128, BN = 128, BK = 32;
  __shared__ __align__(16) uint16_t As[BM][BK];
  __shared__ __align__(16) uint16_t Bs[BN][BK];
  const int t = threadIdx.x;
  const int lane = t & 63, wid = t >> 6;
  const int wr = wid >> 1, wc = wid & 1;
  const int bm = blockIdx.y * BM, bn = blockIdx.x * BN;

  f32x4 acc[4][4] = {};

  const int s_row = t >> 1, s_kh = (t & 1) * 16;
  const uint16_t* Ag = A + (size_t)(bm + s_row) * K + s_kh;
  const uint16_t* Bg = BT + (size_t)(bn + s_row) * K + s_kh;
  const int l15 = lane & 15, kb = (lane >> 4) * 8;

  for (int kt = 0; kt < K / BK; ++kt) {
    __syncthreads();
    u16x8 av0 = *(const u16x8*)(Ag + kt * BK);
    u16x8 av1 = *(const u16x8*)(Ag + kt * BK + 8);
    u16x8 bv0 = *(const u16x8*)(Bg + kt * BK);
    u16x8 bv1 = *(const u16x8*)(Bg + kt * BK + 8);
    *(u16x8*)&As[s_row][s_kh] = av0;
    *(u16x8*)&As[s_row][s_kh + 8] = av1;
    *(u16x8*)&Bs[s_row][s_kh] = bv0;
    *(u16x8*)&Bs[s_row][s_kh + 8] = bv1;
    __syncthreads();
    bf16x8 af[4], bf[4];
#pragma unroll
    for (int m = 0; m < 4; ++m)
      af[m] = *(const bf16x8*)&As[wr * 64 + m * 16 + l15][kb];
#pragma unroll
    for (int n = 0; n < 4; ++n)
      bf[n] = *(const bf16x8*)&Bs[wc * 64 + n * 16 + l15][kb];
#pragma unroll
    for (int m = 0; m < 4; ++m)
#pragma unroll
      for (int n = 0; n < 4; ++n)
        acc[m][n] = __builtin_amdgcn_mfma_f32_16x16x32_bf16(af[m], bf[n],
                                                            acc[m][n], 0, 0, 0);
  }
#pragma unroll
  for (int m = 0; m < 4; ++m) {
    int row = bm + wr * 64 + m * 16 + (lane >> 4) * 4;
#pragma unroll
    for (int n = 0; n < 4; ++n) {
      int col = bn + wc * 64 + n * 16 + l15;
      float bsv = bias[col];
#pragma unroll
      for (int r = 0; r < 4; ++r) {
        float v = acc[m][n][r] + bsv;
        if (relu) v = fmaxf(v, 0.f);
        C[(size_t)(row + r) * N + col] = f2bf(v);
      }
    }
  }
}

// ---------------------------------------------------------------- n3 (N=2)
__global__ __launch_bounds__(256) void k_n3(const uint16_t* __restrict__ h2,
                                            const uint16_t* __restrict__ w3,
                                            const float* __restrict__ b3,
                                            float* __restrict__ out, int M) {
  const int lane = threadIdx.x & 63;
  const int wglob = (blockIdx.x * 256 + threadIdx.x) >> 6;
  const int nw = (gridDim.x * 256) >> 6;
  u16x8 wa = *(const u16x8*)(w3 + lane * 16);
  u16x8 wb = *(const u16x8*)(w3 + lane * 16 + 8);
  u16x8 wc = *(const u16x8*)(w3 + 1024 + lane * 16);
  u16x8 wd = *(const u16x8*)(w3 + 1024 + lane * 16 + 8);
  const float b0 = b3[0], b1 = b3[1];
  for (int row = wglob; row < M; row += nw) {
    const uint16_t* hr = h2 + (size_t)row * 1024;
    u16x8 h0 = *(const u16x8*)(hr + lane * 8);
    u16x8 h1 = *(const u16x8*)(hr + 512 + lane * 8);
    float a0 = 0.f, a1 = 0.f;
#pragma unroll
    for (int e = 0; e < 4; ++e) {
      float h = bf2f(h0[e]);
      a0 = fmaf(h, bf2f(wa[2 * e]), a0);
      a1 = fmaf(h, bf2f(wa[2 * e + 1]), a1);
    }
#pragma unroll
    for (int e = 4; e < 8; ++e) {
      float h = bf2f(h0[e]);
      a0 = fmaf(h, bf2f(wb[2 * e - 8]), a0);
      a1 = fmaf(h, bf2f(wb[2 * e - 7]), a1);
    }
#pragma unroll
    for (int e = 0; e < 4; ++e) {
      float h = bf2f(h1[e]);
      a0 = fmaf(h, bf2f(wc[2 * e]), a0);
      a1 = fmaf(h, bf2f(wc[2 * e + 1]), a1);
    }
#pragma unroll
    for (int e = 4; e < 8; ++e) {
      float h = bf2f(h1[e]);
      a0 = fmaf(h, bf2f(wd[2 * e - 8]), a0);
      a1 = fmaf(h, bf2f(wd[2 * e - 7]), a1);
    }
#pragma unroll
    for (int off = 32; off; off >>= 1) {
      a0 += __shfl_xor(a0, off, 64);
      a1 += __shfl_xor(a1, off, 64);
    }
    if (lane == 0) {
      out[(size_t)row * 2 + 0] = a0 + b0;
      out[(size_t)row * 2 + 1] = a1 + b1;
    }
  }
}

// ---------------------------------------------------------------- launch
extern "C" void kernel_launch(void* const* d_in, const int* in_sizes, int n_in,
                              void* d_out, int out_size, void* d_ws, size_t ws_size,
                              hipStream_t stream) {
  const float* x     = (const float*)d_in[0];
  const float* e_w1  = (const float*)d_in[1];
  const float* e_b1  = (const float*)d_in[2];
  const float* e_w2  = (const float*)d_in[3];
  const float* e_b2  = (const float*)d_in[4];
  const float* hop_w = (const float*)d_in[5];
  const float* n_w1  = (const float*)d_in[6];
  const float* n_b1  = (const float*)d_in[7];
  const float* n_w2  = (const float*)d_in[8];
  const float* n_b2  = (const float*)d_in[9];
  const float* n_w3  = (const float*)d_in[10];
  const float* n_b3  = (const float*)d_in[11];
  float* out = (float*)d_out;
  char* ws = (char*)d_ws;

  float*    h1e  = (float*)(ws + 0);              // 32768x1024 f32 (phase A)
  uint16_t* h1   = (uint16_t*)(ws + 0);           // 32768x1024 bf16 (phase C)
  uint16_t* h2   = (uint16_t*)(ws + 67108864);
  uint16_t* comb = (uint16_t*)(ws + 134217728);
  float*    enc  = (float*)(ws + 171966464);
  uint16_t* w1t  = (uint16_t*)(ws + 180355072);
  uint16_t* w2t  = (uint16_t*)(ws + 181534720);
  uint16_t* w3b  = (uint16_t*)(ws + 183631872);

  k_conv_x<<<8192, 256, 0, stream>>>(x, comb);
  k_convT<<<(576 * 1024 + 255) / 256, 256, 0, stream>>>(n_w1, w1t, 576, 1024);
  k_convT<<<(1024 * 1024 + 255) / 256, 256, 0, stream>>>(n_w2, w2t, 1024, 1024);
  k_conv<<<(2048 + 255) / 256, 256, 0, stream>>>(n_w3, w3b, 2048);

  // encoder (fp32 data, fp64 accumulation -> sign(exact) everywhere)
  k_gemm_f64<128, 64, 16, 8, 4, true>
      <<<dim3(1024 / 64, 32768 / 128), 256, 0, stream>>>(x, e_w1, e_b1, h1e,
                                                         32768, 1024, 512);
  k_gemm_f64<128, 64, 16, 8, 4, false>
      <<<dim3(1, 32768 / 128), 256, 0, stream>>>(h1e, e_w2, e_b2, enc,
                                                 32768, 64, 1024);
  // hopfield — f32 numpy-pairwise-8 order (R10's single change)
  k_hopfield<<<32768 / 128, 128, 0, stream>>>(enc, hop_w, comb);

  // Q-network (bf16 MFMA — ~2e-3 absmax, threshold 6.25e-3)
  k_gemm_bf16<<<dim3(1024 / 128, 32768 / 128), 256, 0, stream>>>(
      comb, w1t, n_b1, h1, 32768, 1024, 576, 1);
  k_gemm_bf16<<<dim3(1024 / 128, 32768 / 128), 256, 0, stream>>>(
      h1, w2t, n_b2, h2, 32768, 1024, 1024, 1);
  k_n3<<<512, 256, 0, stream>>>(h2, w3b, n_b3, out, 32768);
}

// Round 11
// 1193.896 us; speedup vs baseline: 2.4204x; 2.4204x over previous
//
#include <hip/hip_runtime.h>
#include <hip/hip_bf16.h>
#include <stdint.h>
#include <math.h>

typedef __attribute__((ext_vector_type(4))) float f32x4;
typedef __attribute__((ext_vector_type(8))) __bf16 bf16x8;
typedef __attribute__((ext_vector_type(8))) uint16_t u16x8;
typedef __attribute__((ext_vector_type(4))) uint32_t u32x4;

__device__ __forceinline__ uint16_t f2bf(float f) {
  union { float f; uint32_t u; } v; v.f = f;
  uint32_t r = v.u + 0x7FFFu + ((v.u >> 16) & 1u);
  return (uint16_t)(r >> 16);
}
__device__ __forceinline__ float bf2f(uint16_t b) {
  union { uint32_t u; float f; } v; v.u = ((uint32_t)b) << 16;
  return v.f;
}

// ---------------------------------------------------------------- converts
__global__ __launch_bounds__(256) void k_conv_x(const float* __restrict__ x,
                                                uint16_t* __restrict__ comb) {
  int i = blockIdx.x * 256 + threadIdx.x;
  int base = i * 8;
  int row = base >> 9;
  int col = base & 511;
  const float* src = x + base;
  f32x4 a = *(const f32x4*)src;
  f32x4 b = *(const f32x4*)(src + 4);
  u16x8 o;
  o[0] = f2bf(a[0]); o[1] = f2bf(a[1]); o[2] = f2bf(a[2]); o[3] = f2bf(a[3]);
  o[4] = f2bf(b[0]); o[5] = f2bf(b[1]); o[6] = f2bf(b[2]); o[7] = f2bf(b[3]);
  *(u16x8*)(comb + (size_t)row * 576 + col) = o;
}

__global__ __launch_bounds__(256) void k_convT(const float* __restrict__ W,
                                               uint16_t* __restrict__ WT,
                                               int K, int N) {
  int i = blockIdx.x * 256 + threadIdx.x;
  if (i < K * N) {
    int k = i / N, n = i % N;
    WT[n * K + k] = f2bf(W[i]);
  }
}

__global__ __launch_bounds__(256) void k_conv(const float* __restrict__ W,
                                              uint16_t* __restrict__ O, int n) {
  int i = blockIdx.x * 256 + threadIdx.x;
  if (i < n) O[i] = f2bf(W[i]);
}

// ---------------------------------------------------------------- encoder
// f32 OpenBLAS-replica encoder (R4/R7 kernel). R2==R7 proved this encoder
// and the fp64 one give BIT-IDENTICAL pipeline output (all probe bits
// equal on this data); f32 is ~2x the fp64 vector rate.
template <int K, bool RELU>
__global__ __launch_bounds__(256)
void k_enc(const float* __restrict__ A, const float* __restrict__ W,
           const float* __restrict__ bias, float* __restrict__ C, int N) {
  __shared__ __align__(16) float xs[64][136];  // [k][m], padded
  __shared__ __align__(16) float ws[64][68];   // [k][n], padded
  const int t = threadIdx.x;
  const int m0 = blockIdx.y * 128, n0 = blockIdx.x * 64;
  const int mg = t >> 4, ng = t & 15;

  float res[8][4], acc[8][4];
#pragma unroll
  for (int i = 0; i < 8; ++i)
#pragma unroll
    for (int j = 0; j < 4; ++j) { res[i][j] = 0.f; acc[i][j] = 0.f; }

  const int xr = t >> 1, xk = (t & 1) * 32;
  const int wrr = t >> 2, wj = (t & 3) * 16;

  for (int c = 0; c < K / 64; ++c) {
    const int k0 = c * 64;
    if (k0 > 0 && (k0 % 384) == 0) {  // OpenBLAS kc-panel boundary (Q=384)
#pragma unroll
      for (int i = 0; i < 8; ++i)
#pragma unroll
        for (int j = 0; j < 4; ++j) { res[i][j] += acc[i][j]; acc[i][j] = 0.f; }
    }
    __syncthreads();
#pragma unroll
    for (int u = 0; u < 8; ++u) {
      f32x4 v = *(const f32x4*)(A + (size_t)(m0 + xr) * K + k0 + xk + u * 4);
      xs[xk + u * 4 + 0][xr] = v[0];
      xs[xk + u * 4 + 1][xr] = v[1];
      xs[xk + u * 4 + 2][xr] = v[2];
      xs[xk + u * 4 + 3][xr] = v[3];
    }
#pragma unroll
    for (int u = 0; u < 4; ++u)
      *(f32x4*)&ws[wrr][wj + u * 4] =
          *(const f32x4*)(W + (size_t)(k0 + wrr) * N + n0 + wj + u * 4);
    __syncthreads();
#pragma unroll
    for (int k = 0; k < 64; ++k) {
      f32x4 x0 = *(const f32x4*)&xs[k][mg * 8];
      f32x4 x1 = *(const f32x4*)&xs[k][mg * 8 + 4];
      f32x4 wv = *(const f32x4*)&ws[k][ng * 4];
#pragma unroll
      for (int j = 0; j < 4; ++j) {
        acc[0][j] = fmaf(x0[0], wv[j], acc[0][j]);
        acc[1][j] = fmaf(x0[1], wv[j], acc[1][j]);
        acc[2][j] = fmaf(x0[2], wv[j], acc[2][j]);
        acc[3][j] = fmaf(x0[3], wv[j], acc[3][j]);
        acc[4][j] = fmaf(x1[0], wv[j], acc[4][j]);
        acc[5][j] = fmaf(x1[1], wv[j], acc[5][j]);
        acc[6][j] = fmaf(x1[2], wv[j], acc[6][j]);
        acc[7][j] = fmaf(x1[3], wv[j], acc[7][j]);
      }
    }
  }
#pragma unroll
  for (int i = 0; i < 8; ++i)
#pragma unroll
    for (int j = 0; j < 4; ++j) res[i][j] += acc[i][j];  // final panel join

#pragma unroll
  for (int i = 0; i < 8; ++i) {
    f32x4 o;
#pragma unroll
    for (int j = 0; j < 4; ++j) {
      float v = res[i][j] + bias[n0 + ng * 4 + j];
      if (RELU) v = fmaxf(v, 0.f);
      o[j] = v;
    }
    *(f32x4*)(C + (size_t)(m0 + mg * 8 + i) * N + n0 + ng * 4) = o;
  }
}

// ---------------------------------------------------------------- Hopfield
// PASSING arithmetic (R10): f32 state, numpy pairwise-8 tree, tie -> -1.
// Restructured 8-lanes-per-sample for perf (R10 was 3.8% occupancy +
// scratch-spilled via runtime sr[knife] store — rule #20):
//   lane l owns elements 8c+l  == numpy's partial slot l
//   r_l chain ascending c (bitwise = numpy partial)
//   shfl_xor 1,2,4 reduce == ((r0+r1)+(r2+r3))+((r4+r5)+(r6+r7)) bitwise
//   (commutativity: every lane holds the identical f32 value)
// Knife flip via bitmask (no runtime array index -> registers, no scratch).
#define KNIFE_TAU 1e-6f

__device__ __forceinline__ void retrieve8(float (&s)[8],
                                          const float (*w)[64], int l) {
  for (int it = 0; it < 10; ++it) {
    bool changed = false;
#pragma unroll
    for (int i = 0; i < 64; ++i) {
      float r = 0.f;
#pragma unroll
      for (int c = 0; c < 8; ++c)
        r = fmaf(s[c], w[i][8 * c + l], r);
      r += __shfl_xor(r, 1);
      r += __shfl_xor(r, 2);
      r += __shfl_xor(r, 4);
      float ns = r > 0.f ? 1.f : -1.f;   // np: where(act > 0, 1, -1)
      bool own = ((i & 7) == l);
      float cur = s[i >> 3];
      float nv = own ? ns : cur;          // only owner lane updates
      changed |= (nv != cur);
      s[i >> 3] = nv;
    }
    if (!__any(changed)) break;  // fixed point: further sweeps are identity
  }
}

__device__ __forceinline__ uint64_t gather_mask(const float (&s)[8], int g) {
  uint64_t m = 0;
#pragma unroll
  for (int c = 0; c < 8; ++c) {
    unsigned long long b = __ballot(s[c] > 0.f);
    m |= (uint64_t)((b >> (g * 8)) & 0xFFull) << (8 * c);
  }
  return m;
}

__global__ __launch_bounds__(256) void k_hopfield(const float* __restrict__ enc,
                                                  const float* __restrict__ hw,
                                                  uint16_t* __restrict__ comb) {
  __shared__ __align__(16) float w[64][64];
  const int t = threadIdx.x;
#pragma unroll
  for (int i = 0; i < 4; ++i)
    ((f32x4*)&w[0][0])[t * 4 + i] = ((const f32x4*)hw)[t * 4 + i];
  __syncthreads();

  const int lane = t & 63, wv = t >> 6;
  const int g = lane >> 3, l = lane & 7;
  const int sid = (blockIdx.x * 4 + wv) * 8 + g;
  const float* er = enc + (size_t)sid * 64;

  uint32_t imask = 0;
  int kc = -1;
  bool kpos = false;
#pragma unroll
  for (int c = 0; c < 8; ++c) {
    float v = er[8 * c + l];
    if (v > 0.f) imask |= (1u << c);
    if (kc < 0 && fabsf(v) < KNIFE_TAU) { kc = c; kpos = v > 0.f; }
  }
  unsigned long long kb = __ballot(kc >= 0);
  uint32_t gbits = (uint32_t)((kb >> (g * 8)) & 0xFFull);
  bool hasknife = gbits != 0;
  int klane = g * 8 + (__ffs(gbits) - 1);  // valid only if hasknife
  bool is_kl = hasknife && (lane == klane);
  uint32_t kbit = (kc >= 0) ? (1u << (kc & 7)) : 0u;

  // run A: knife bit (if any) forced +1 on its owner lane
  uint32_t ma_bits = is_kl ? (imask | kbit) : imask;
  float sA[8];
#pragma unroll
  for (int c = 0; c < 8; ++c) sA[c] = ((ma_bits >> c) & 1u) ? 1.f : -1.f;
  retrieve8(sA, w, l);
  uint64_t mA = gather_mask(sA, g);
  uint64_t m = mA;

  if (__any(hasknife)) {
    if (hasknife) {  // group-uniform predicate: whole groups active
      uint32_t mb_bits = is_kl ? (imask & ~kbit) : imask;
      float sB[8];
#pragma unroll
      for (int c = 0; c < 8; ++c) sB[c] = ((mb_bits >> c) & 1u) ? 1.f : -1.f;
      retrieve8(sB, w, l);
      uint64_t mB = gather_mask(sB, g);
      if (mA != mB) {
        int kp = __shfl(kpos ? 1 : 0, klane);
        m = kp ? mA : mB;  // exact-sign pick (inert per R9; healing covers)
      }
    }
  }

  // write: lane l owns output elements 8l..8l+7 (16B, coalesced)
  uint32_t byte = (uint32_t)((m >> (8 * l)) & 0xFFull);
  u32x4 o;
#pragma unroll
  for (int p = 0; p < 4; ++p) {
    uint32_t lo = ((byte >> (2 * p)) & 1u) ? 0x3F80u : 0u;
    uint32_t hi = ((byte >> (2 * p + 1)) & 1u) ? 0x3F800000u : 0u;
    o[p] = lo | hi;
  }
  *(u32x4*)(comb + (size_t)sid * 576 + 512 + l * 8) = o;
}

// ---------------------------------------------------------------- bf16 MFMA GEMM
__global__ __launch_bounds__(256)
void k_gemm_bf16(const uint16_t* __restrict__ A, const uint16_t* __restrict__ BT,
                 const float* __restrict__ bias, uint16_t* __restrict__ C,
                 int M, int N, int K, int relu) {
  constexpr int BM = 128, BN = 128, BK = 32;
  __shared__ __align__(16) uint16_t As[BM][BK];
  __shared__ __align__(16) uint16_t Bs[BN][BK];
  const int t = threadIdx.x;
  const int lane = t & 63, wid = t >> 6;
  const int wr = wid >> 1, wc = wid & 1;
  const int bm = blockIdx.y * BM, bn = blockIdx.x * BN;

  f32x4 acc[4][4] = {};

  const int s_row = t >> 1, s_kh = (t & 1) * 16;
  const uint16_t* Ag = A + (size_t)(bm + s_row) * K + s_kh;
  const uint16_t* Bg = BT + (size_t)(bn + s_row) * K + s_kh;
  const int l15 = lane & 15, kb = (lane >> 4) * 8;

  for (int kt = 0; kt < K / BK; ++kt) {
    __syncthreads();
    u16x8 av0 = *(const u16x8*)(Ag + kt * BK);
    u16x8 av1 = *(const u16x8*)(Ag + kt * BK + 8);
    u16x8 bv0 = *(const u16x8*)(Bg + kt * BK);
    u16x8 bv1 = *(const u16x8*)(Bg + kt * BK + 8);
    *(u16x8*)&As[s_row][s_kh] = av0;
    *(u16x8*)&As[s_row][s_kh + 8] = av1;
    *(u16x8*)&Bs[s_row][s_kh] = bv0;
    *(u16x8*)&Bs[s_row][s_kh + 8] = bv1;
    __syncthreads();
    bf16x8 af[4], bf[4];
#pragma unroll
    for (int m = 0; m < 4; ++m)
      af[m] = *(const bf16x8*)&As[wr * 64 + m * 16 + l15][kb];
#pragma unroll
    for (int n = 0; n < 4; ++n)
      bf[n] = *(const bf16x8*)&Bs[wc * 64 + n * 16 + l15][kb];
#pragma unroll
    for (int m = 0; m < 4; ++m)
#pragma unroll
      for (int n = 0; n < 4; ++n)
        acc[m][n] = __builtin_amdgcn_mfma_f32_16x16x32_bf16(af[m], bf[n],
                                                            acc[m][n], 0, 0, 0);
  }
#pragma unroll
  for (int m = 0; m < 4; ++m) {
    int row = bm + wr * 64 + m * 16 + (lane >> 4) * 4;
#pragma unroll
    for (int n = 0; n < 4; ++n) {
      int col = bn + wc * 64 + n * 16 + l15;
      float bsv = bias[col];
#pragma unroll
      for (int r = 0; r < 4; ++r) {
        float v = acc[m][n][r] + bsv;
        if (relu) v = fmaxf(v, 0.f);
        C[(size_t)(row + r) * N + col] = f2bf(v);
      }
    }
  }
}

// ---------------------------------------------------------------- n3 (N=2)
__global__ __launch_bounds__(256) void k_n3(const uint16_t* __restrict__ h2,
                                            const uint16_t* __restrict__ w3,
                                            const float* __restrict__ b3,
                                            float* __restrict__ out, int M) {
  const int lane = threadIdx.x & 63;
  const int wglob = (blockIdx.x * 256 + threadIdx.x) >> 6;
  const int nw = (gridDim.x * 256) >> 6;
  u16x8 wa = *(const u16x8*)(w3 + lane * 16);
  u16x8 wb = *(const u16x8*)(w3 + lane * 16 + 8);
  u16x8 wc = *(const u16x8*)(w3 + 1024 + lane * 16);
  u16x8 wd = *(const u16x8*)(w3 + 1024 + lane * 16 + 8);
  const float b0 = b3[0], b1 = b3[1];
  for (int row = wglob; row < M; row += nw) {
    const uint16_t* hr = h2 + (size_t)row * 1024;
    u16x8 h0 = *(const u16x8*)(hr + lane * 8);
    u16x8 h1 = *(const u16x8*)(hr + 512 + lane * 8);
    float a0 = 0.f, a1 = 0.f;
#pragma unroll
    for (int e = 0; e < 4; ++e) {
      float h = bf2f(h0[e]);
      a0 = fmaf(h, bf2f(wa[2 * e]), a0);
      a1 = fmaf(h, bf2f(wa[2 * e + 1]), a1);
    }
#pragma unroll
    for (int e = 4; e < 8; ++e) {
      float h = bf2f(h0[e]);
      a0 = fmaf(h, bf2f(wb[2 * e - 8]), a0);
      a1 = fmaf(h, bf2f(wb[2 * e - 7]), a1);
    }
#pragma unroll
    for (int e = 0; e < 4; ++e) {
      float h = bf2f(h1[e]);
      a0 = fmaf(h, bf2f(wc[2 * e]), a0);
      a1 = fmaf(h, bf2f(wc[2 * e + 1]), a1);
    }
#pragma unroll
    for (int e = 4; e < 8; ++e) {
      float h = bf2f(h1[e]);
      a0 = fmaf(h, bf2f(wd[2 * e - 8]), a0);
      a1 = fmaf(h, bf2f(wd[2 * e - 7]), a1);
    }
#pragma unroll
    for (int off = 32; off; off >>= 1) {
      a0 += __shfl_xor(a0, off, 64);
      a1 += __shfl_xor(a1, off, 64);
    }
    if (lane == 0) {
      out[(size_t)row * 2 + 0] = a0 + b0;
      out[(size_t)row * 2 + 1] = a1 + b1;
    }
  }
}

// ---------------------------------------------------------------- launch
extern "C" void kernel_launch(void* const* d_in, const int* in_sizes, int n_in,
                              void* d_out, int out_size, void* d_ws, size_t ws_size,
                              hipStream_t stream) {
  const float* x     = (const float*)d_in[0];
  const float* e_w1  = (const float*)d_in[1];
  const float* e_b1  = (const float*)d_in[2];
  const float* e_w2  = (const float*)d_in[3];
  const float* e_b2  = (const float*)d_in[4];
  const float* hop_w = (const float*)d_in[5];
  const float* n_w1  = (const float*)d_in[6];
  const float* n_b1  = (const float*)d_in[7];
  const float* n_w2  = (const float*)d_in[8];
  const float* n_b2  = (const float*)d_in[9];
  const float* n_w3  = (const float*)d_in[10];
  const float* n_b3  = (const float*)d_in[11];
  float* out = (float*)d_out;
  char* ws = (char*)d_ws;

  float*    h1e  = (float*)(ws + 0);              // 32768x1024 f32 (phase A)
  uint16_t* h1   = (uint16_t*)(ws + 0);           // 32768x1024 bf16 (phase C)
  uint16_t* h2   = (uint16_t*)(ws + 67108864);
  uint16_t* comb = (uint16_t*)(ws + 134217728);
  float*    enc  = (float*)(ws + 171966464);
  uint16_t* w1t  = (uint16_t*)(ws + 180355072);
  uint16_t* w2t  = (uint16_t*)(ws + 181534720);
  uint16_t* w3b  = (uint16_t*)(ws + 183631872);

  k_conv_x<<<8192, 256, 0, stream>>>(x, comb);
  k_convT<<<(576 * 1024 + 255) / 256, 256, 0, stream>>>(n_w1, w1t, 576, 1024);
  k_convT<<<(1024 * 1024 + 255) / 256, 256, 0, stream>>>(n_w2, w2t, 1024, 1024);
  k_conv<<<(2048 + 255) / 256, 256, 0, stream>>>(n_w3, w3b, 2048);

  // encoder — f32 OpenBLAS replica (bit-equivalent to fp64 per R2==R7, 2x rate)
  k_enc<512, true><<<dim3(1024 / 64, 32768 / 128), 256, 0, stream>>>(
      x, e_w1, e_b1, h1e, 1024);
  k_enc<1024, false><<<dim3(1, 32768 / 128), 256, 0, stream>>>(
      h1e, e_w2, e_b2, enc, 64);

  // hopfield — same arithmetic as R10 pass, 8-lane/sample + no scratch
  k_hopfield<<<32768 / 32, 256, 0, stream>>>(enc, hop_w, comb);

  // Q-network (bf16 MFMA)
  k_gemm_bf16<<<dim3(1024 / 128, 32768 / 128), 256, 0, stream>>>(
      comb, w1t, n_b1, h1, 32768, 1024, 576, 1);
  k_gemm_bf16<<<dim3(1024 / 128, 32768 / 128), 256, 0, stream>>>(
      h1, w2t, n_b2, h2, 32768, 1024, 1024, 1);
  k_n3<<<512, 256, 0, stream>>>(h2, w3b, n_b3, out, 32768);
}